// Round 1
// baseline (11089.671 us; speedup 1.0000x reference)
//
#include <hip/hip_runtime.h>
#include <math.h>

typedef __attribute__((ext_vector_type(8))) short short8;
typedef __attribute__((ext_vector_type(4))) float floatx4;

#define NB 256      // batch
#define NH 512      // hidden
#define NXP 256     // x' dim
#define NT 512      // timesteps
#define DXL 64
#define DSM 32

__device__ __forceinline__ unsigned short f2bf(float f) {
    union { float f; unsigned u; } x; x.f = f;
    unsigned r = x.u + 0x7FFFu + ((x.u >> 16) & 1u);
    return (unsigned short)(r >> 16);
}
__device__ __forceinline__ float sigmoidf_(float x) { return 1.0f / (1.0f + __expf(-x)); }

__device__ __forceinline__ short8 ld8f32_bf(const float* __restrict__ p) {
    float4 u = *(const float4*)p;
    float4 v = *(const float4*)(p + 4);
    short8 r;
    r[0] = (short)f2bf(u.x); r[1] = (short)f2bf(u.y);
    r[2] = (short)f2bf(u.z); r[3] = (short)f2bf(u.w);
    r[4] = (short)f2bf(v.x); r[5] = (short)f2bf(v.y);
    r[6] = (short)f2bf(v.z); r[7] = (short)f2bf(v.w);
    return r;
}

__global__ void k_cvt(const float* __restrict__ src, unsigned short* __restrict__ dst, int n) {
    int i = blockIdx.x * blockDim.x + threadIdx.x;
    int stride = gridDim.x * blockDim.x;
    for (; i < n; i += stride) dst[i] = f2bf(src[i]);
}

// x' = tanh(h @ Wt_h^T + xcat @ Wt_x^T + bt)
// grid (8, 4): x = batch-block (32 rows), y = n-block (64 cols). block = 128 (2 waves),
// wave w covers n0..n0+31. Fragments loaded direct from global (L2-resident).
__global__ __launch_bounds__(128)
void k_xprime(const unsigned short* __restrict__ hbf,
              const float* __restrict__ xl, const float* __restrict__ xt_,
              const float* __restrict__ xw, const float* __restrict__ xs,
              const unsigned short* __restrict__ Wth, const unsigned short* __restrict__ Wtx,
              const float* __restrict__ bt, unsigned short* __restrict__ xpbf, int t)
{
    const int lane = threadIdx.x & 63;
    const int w    = threadIdx.x >> 6;
    const int lr   = lane & 15;          // row (A) / col (B) within 16x16 frag
    const int lk   = (lane >> 4) * 8;    // k offset within K=32 slice
    const int b0   = blockIdx.x * 32;
    const int n0   = blockIdx.y * 64 + w * 32;

    floatx4 acc[2][2];
    #pragma unroll
    for (int mi = 0; mi < 2; ++mi)
        #pragma unroll
        for (int ni = 0; ni < 2; ++ni) acc[mi][ni] = (floatx4){0.f, 0.f, 0.f, 0.f};

    // ---- h part, K = 512 ----
    const unsigned short* A0 = hbf + (size_t)(b0 + lr) * NH + lk;
    const unsigned short* A1 = hbf + (size_t)(b0 + 16 + lr) * NH + lk;
    const unsigned short* B0 = Wth + (size_t)(n0 + lr) * NH + lk;
    const unsigned short* B1 = Wth + (size_t)(n0 + 16 + lr) * NH + lk;
    for (int kb = 0; kb < NH; kb += 32) {
        short8 a0 = *(const short8*)(A0 + kb);
        short8 a1 = *(const short8*)(A1 + kb);
        short8 q0 = *(const short8*)(B0 + kb);
        short8 q1 = *(const short8*)(B1 + kb);
        acc[0][0] = __builtin_amdgcn_mfma_f32_16x16x32_bf16(a0, q0, acc[0][0], 0, 0, 0);
        acc[0][1] = __builtin_amdgcn_mfma_f32_16x16x32_bf16(a0, q1, acc[0][1], 0, 0, 0);
        acc[1][0] = __builtin_amdgcn_mfma_f32_16x16x32_bf16(a1, q0, acc[1][0], 0, 0, 0);
        acc[1][1] = __builtin_amdgcn_mfma_f32_16x16x32_bf16(a1, q1, acc[1][1], 0, 0, 0);
    }

    // ---- x part, K = 160 in 5 chunks of 32 (chunk boundaries align with the 4 arrays) ----
    const unsigned short* BX0 = Wtx + (size_t)(n0 + lr) * 160 + lk;
    const unsigned short* BX1 = Wtx + (size_t)(n0 + 16 + lr) * 160 + lk;
    const size_t r0 = (size_t)(b0 + lr);
    const size_t r1 = (size_t)(b0 + 16 + lr);
    #pragma unroll
    for (int c = 0; c < 5; ++c) {
        const float *pa0, *pa1;
        if (c < 2) {
            pa0 = xl + (r0 * NT + t) * DXL + c * 32 + lk;
            pa1 = xl + (r1 * NT + t) * DXL + c * 32 + lk;
        } else if (c == 2) {
            pa0 = xt_ + (r0 * NT + t) * DSM + lk;
            pa1 = xt_ + (r1 * NT + t) * DSM + lk;
        } else if (c == 3) {
            pa0 = xw + (r0 * NT + t) * DSM + lk;
            pa1 = xw + (r1 * NT + t) * DSM + lk;
        } else {
            pa0 = xs + (r0 * NT + t) * DSM + lk;
            pa1 = xs + (r1 * NT + t) * DSM + lk;
        }
        short8 a0 = ld8f32_bf(pa0);
        short8 a1 = ld8f32_bf(pa1);
        short8 q0 = *(const short8*)(BX0 + c * 32);
        short8 q1 = *(const short8*)(BX1 + c * 32);
        acc[0][0] = __builtin_amdgcn_mfma_f32_16x16x32_bf16(a0, q0, acc[0][0], 0, 0, 0);
        acc[0][1] = __builtin_amdgcn_mfma_f32_16x16x32_bf16(a0, q1, acc[0][1], 0, 0, 0);
        acc[1][0] = __builtin_amdgcn_mfma_f32_16x16x32_bf16(a1, q0, acc[1][0], 0, 0, 0);
        acc[1][1] = __builtin_amdgcn_mfma_f32_16x16x32_bf16(a1, q1, acc[1][1], 0, 0, 0);
    }

    // epilogue: C/D layout col = lane&15, row = (lane>>4)*4 + reg  [m89-verified]
    #pragma unroll
    for (int mi = 0; mi < 2; ++mi) {
        #pragma unroll
        for (int ni = 0; ni < 2; ++ni) {
            int col = n0 + ni * 16 + lr;
            float btv = bt[col];
            #pragma unroll
            for (int rg = 0; rg < 4; ++rg) {
                int row = b0 + mi * 16 + (lane >> 4) * 4 + rg;
                xpbf[(size_t)row * NXP + col] = f2bf(tanhf(acc[mi][ni][rg] + btv));
            }
        }
    }
}

// gates + h update. grid (4, 32): x = batch-block (64 rows), y = j-block (16 cols).
// block = 128 (2 waves); wave w covers 32 batch rows, computes r,z,xn,hn for its 16 j's.
__global__ __launch_bounds__(128)
void k_step(const float* __restrict__ hf, const unsigned short* __restrict__ hbf,
            const unsigned short* __restrict__ xpbf,
            const unsigned short* __restrict__ Wih, const unsigned short* __restrict__ Whh,
            const float* __restrict__ bih, const float* __restrict__ bhh,
            float* __restrict__ houtf, unsigned short* __restrict__ houtbf)
{
    const int lane = threadIdx.x & 63;
    const int w    = threadIdx.x >> 6;
    const int lr   = lane & 15;
    const int lk   = (lane >> 4) * 8;
    const int b0   = blockIdx.x * 64 + w * 32;
    const int j0   = blockIdx.y * 16;

    floatx4 ar[2], az[2], axn[2], ahn[2];
    #pragma unroll
    for (int mi = 0; mi < 2; ++mi) {
        ar[mi] = (floatx4){0.f, 0.f, 0.f, 0.f};
        az[mi] = (floatx4){0.f, 0.f, 0.f, 0.f};
        axn[mi] = (floatx4){0.f, 0.f, 0.f, 0.f};
        ahn[mi] = (floatx4){0.f, 0.f, 0.f, 0.f};
    }

    // ---- loop 1: x' @ W_ih^T, K = 256 ----
    {
        const unsigned short* A0 = xpbf + (size_t)(b0 + lr) * NXP + lk;
        const unsigned short* A1 = xpbf + (size_t)(b0 + 16 + lr) * NXP + lk;
        const unsigned short* Br = Wih + (size_t)(j0 + lr) * NXP + lk;
        const unsigned short* Bz = Wih + (size_t)(512 + j0 + lr) * NXP + lk;
        const unsigned short* Bn = Wih + (size_t)(1024 + j0 + lr) * NXP + lk;
        for (int kb = 0; kb < NXP; kb += 32) {
            short8 a0 = *(const short8*)(A0 + kb);
            short8 a1 = *(const short8*)(A1 + kb);
            short8 br = *(const short8*)(Br + kb);
            short8 bz = *(const short8*)(Bz + kb);
            short8 bn = *(const short8*)(Bn + kb);
            ar[0]  = __builtin_amdgcn_mfma_f32_16x16x32_bf16(a0, br, ar[0], 0, 0, 0);
            ar[1]  = __builtin_amdgcn_mfma_f32_16x16x32_bf16(a1, br, ar[1], 0, 0, 0);
            az[0]  = __builtin_amdgcn_mfma_f32_16x16x32_bf16(a0, bz, az[0], 0, 0, 0);
            az[1]  = __builtin_amdgcn_mfma_f32_16x16x32_bf16(a1, bz, az[1], 0, 0, 0);
            axn[0] = __builtin_amdgcn_mfma_f32_16x16x32_bf16(a0, bn, axn[0], 0, 0, 0);
            axn[1] = __builtin_amdgcn_mfma_f32_16x16x32_bf16(a1, bn, axn[1], 0, 0, 0);
        }
    }
    // ---- loop 2: h @ W_hh^T, K = 512 (r,z accumulate on top; n goes to separate acc) ----
    {
        const unsigned short* A0 = hbf + (size_t)(b0 + lr) * NH + lk;
        const unsigned short* A1 = hbf + (size_t)(b0 + 16 + lr) * NH + lk;
        const unsigned short* Br = Whh + (size_t)(j0 + lr) * NH + lk;
        const unsigned short* Bz = Whh + (size_t)(512 + j0 + lr) * NH + lk;
        const unsigned short* Bn = Whh + (size_t)(1024 + j0 + lr) * NH + lk;
        for (int kb = 0; kb < NH; kb += 32) {
            short8 a0 = *(const short8*)(A0 + kb);
            short8 a1 = *(const short8*)(A1 + kb);
            short8 br = *(const short8*)(Br + kb);
            short8 bz = *(const short8*)(Bz + kb);
            short8 bn = *(const short8*)(Bn + kb);
            ar[0]  = __builtin_amdgcn_mfma_f32_16x16x32_bf16(a0, br, ar[0], 0, 0, 0);
            ar[1]  = __builtin_amdgcn_mfma_f32_16x16x32_bf16(a1, br, ar[1], 0, 0, 0);
            az[0]  = __builtin_amdgcn_mfma_f32_16x16x32_bf16(a0, bz, az[0], 0, 0, 0);
            az[1]  = __builtin_amdgcn_mfma_f32_16x16x32_bf16(a1, bz, az[1], 0, 0, 0);
            ahn[0] = __builtin_amdgcn_mfma_f32_16x16x32_bf16(a0, bn, ahn[0], 0, 0, 0);
            ahn[1] = __builtin_amdgcn_mfma_f32_16x16x32_bf16(a1, bn, ahn[1], 0, 0, 0);
        }
    }

    // epilogue
    const int j = j0 + lr;
    const float bi_r = bih[j],        bh_r = bhh[j];
    const float bi_z = bih[512 + j],  bh_z = bhh[512 + j];
    const float bi_n = bih[1024 + j], bh_n = bhh[1024 + j];
    #pragma unroll
    for (int mi = 0; mi < 2; ++mi) {
        #pragma unroll
        for (int rg = 0; rg < 4; ++rg) {
            int b = b0 + mi * 16 + (lane >> 4) * 4 + rg;
            float rgate = sigmoidf_(ar[mi][rg] + bi_r + bh_r);
            float zgate = sigmoidf_(az[mi][rg] + bi_z + bh_z);
            float ngate = tanhf(axn[mi][rg] + bi_n + rgate * (ahn[mi][rg] + bh_n));
            float hold  = hf[(size_t)b * NH + j];
            float hnew  = (1.0f - zgate) * ngate + zgate * hold;
            houtf[(size_t)b * NH + j]  = hnew;
            houtbf[(size_t)b * NH + j] = f2bf(hnew);
        }
    }
}

extern "C" void kernel_launch(void* const* d_in, const int* in_sizes, int n_in,
                              void* d_out, int out_size, void* d_ws, size_t ws_size,
                              hipStream_t stream)
{
    const float* xl  = (const float*)d_in[0];
    const float* xt_ = (const float*)d_in[1];
    const float* xw  = (const float*)d_in[2];
    const float* xs  = (const float*)d_in[3];
    const float* Wih = (const float*)d_in[4];
    const float* Whh = (const float*)d_in[5];
    const float* bih = (const float*)d_in[6];
    const float* bhh = (const float*)d_in[7];
    const float* Wth = (const float*)d_in[8];
    const float* Wtx = (const float*)d_in[9];
    const float* bt  = (const float*)d_in[10];

    // workspace layout
    char* p = (char*)d_ws;
    float* hfA = (float*)p;           p += (size_t)NB * NH * 4;
    float* hfB = (float*)p;           p += (size_t)NB * NH * 4;
    unsigned short* hbA = (unsigned short*)p;  p += (size_t)NB * NH * 2;
    unsigned short* hbB = (unsigned short*)p;  p += (size_t)NB * NH * 2;
    unsigned short* xpb = (unsigned short*)p;  p += (size_t)NB * NXP * 2;
    unsigned short* Wihb = (unsigned short*)p; p += (size_t)1536 * 256 * 2;
    unsigned short* Whhb = (unsigned short*)p; p += (size_t)1536 * 512 * 2;
    unsigned short* Wthb = (unsigned short*)p; p += (size_t)256 * 512 * 2;
    unsigned short* Wtxb = (unsigned short*)p; p += (size_t)256 * 160 * 2;
    if ((size_t)(p - (char*)d_ws) > ws_size) return;  // fail loudly (validation will catch)

    // one-time (per call) weight conversions to bf16
    k_cvt<<<256, 256, 0, stream>>>(Wih, Wihb, 1536 * 256);
    k_cvt<<<256, 256, 0, stream>>>(Whh, Whhb, 1536 * 512);
    k_cvt<<<64, 256, 0, stream>>>(Wth, Wthb, 256 * 512);
    k_cvt<<<32, 256, 0, stream>>>(Wtx, Wtxb, 256 * 160);
    hipMemsetAsync(hfA, 0, (size_t)NB * NH * 4, stream);
    hipMemsetAsync(hbA, 0, (size_t)NB * NH * 2, stream);

    float* hin_f = hfA;  unsigned short* hin_b = hbA;
    float* hout_f = hfB; unsigned short* hout_b = hbB;
    for (int t = 0; t < NT; ++t) {
        k_xprime<<<dim3(8, 4), 128, 0, stream>>>(hin_b, xl, xt_, xw, xs, Wthb, Wtxb, bt, xpb, t);
        float* of = (t == NT - 1) ? (float*)d_out : hout_f;
        k_step<<<dim3(4, 32), 128, 0, stream>>>(hin_f, hin_b, xpb, Wihb, Whhb, bih, bhh, of, hout_b);
        float* tf = hin_f; hin_f = hout_f; hout_f = tf;
        unsigned short* tb = hin_b; hin_b = hout_b; hout_b = tb;
    }
}